// Round 24
// baseline (37.996 us; speedup 1.0000x reference)
//
#include <hip/hip_runtime.h>
#include <cmath>

#define BN 4096      // B*N
#define NN 64
#define GAUSS 25
#define FD 128

typedef __attribute__((ext_vector_type(8))) short bf16x8;
typedef __attribute__((ext_vector_type(4))) float f32x4;

__device__ __forceinline__ float softplus_f(float x) {
    const float t = __expf(-fabsf(x));
    return fmaxf(x, 0.f) + __logf(1.f + t);
}
// single-op packed bf16 convert (RNE)
__device__ __forceinline__ unsigned int cvtpk(float lo, float hi) {
    unsigned int r;
    asm("v_cvt_pk_bf16_f32 %0, %1, %2" : "=v"(r) : "v"(lo), "v"(hi));
    return r;
}
// scalar fallback (kA packing of scattered weight elems)
__device__ __forceinline__ unsigned short f2b(float f) {
    unsigned int u = __float_as_uint(f);
    unsigned int r = (u + 0x7FFFu + ((u >> 16) & 1u)) >> 16;
    return (unsigned short)r;
}
__device__ __forceinline__ bf16x8 pack8(const float4 p0, const float4 p1) {
    union { unsigned int u[4]; bf16x8 v; } r;
    r.u[0] = cvtpk(p0.x, p0.y); r.u[1] = cvtpk(p0.z, p0.w);
    r.u[2] = cvtpk(p1.x, p1.y); r.u[3] = cvtpk(p1.z, p1.w);
    return r.v;
}

// ---------------------------------------------------------------------------
// KA = k0 + k1 fused.  Grid 256 x 512.
// wf1tA row g==25 carries bf1 (bias folded into the h1 MFMA).
// R24: win2fB LDS pack now COALESCED (8 float4 loads + scattered ds_write_b16
// via forward slot map) instead of 32 stride-512B scattered dword loads.
// ---------------------------------------------------------------------------
__global__ __launch_bounds__(512) void kA_prep_embed_y(
    const float* __restrict__ emb, const int* __restrict__ zn,
    const float* __restrict__ wf1, const float* __restrict__ bf1,
    const float* __restrict__ wf2,
    const float* __restrict__ w_in2f, const float* __restrict__ w_f2out,
    const float* __restrict__ w_dense,
    unsigned short* __restrict__ wf1tA, unsigned short* __restrict__ wf2tA,
    unsigned short* __restrict__ wf2outB, unsigned short* __restrict__ wdenseB,
    float* __restrict__ y, float* __restrict__ out)
{
    const int t = threadIdx.x;
    const int w = t >> 6, lane = t & 63, lr = lane & 15, lg = lane >> 4;
    __shared__ unsigned short s_w[16384];   // 32KB: win2fB frags

    {
        const int idx = blockIdx.x * 512 + t;
        if (idx < 4096) {
            const int e = idx & 7, l = (idx >> 3) & 63, ft = idx >> 9;
            const int f = ft * 16 + (l & 15);
            const int g = 8 * (l >> 4) + e;
            wf1tA[idx] = (g < GAUSS) ? f2b(wf1[g * FD + f])
                       : (g == GAUSS ? f2b(bf1[f]) : (unsigned short)0);
        } else if (idx < 20480) {
            const int i = idx - 4096;
            const int e = i & 7, l = (i >> 3) & 63, ct = (i >> 9) & 7, ks = i >> 12;
            wf2tA[i] = f2b(wf2[(ks * 32 + 8 * (l >> 4) + e) * FD + ct * 16 + (l & 15)]);
        } else if (idx < 36864) {
            const int i = idx - 20480;
            const int e = i & 7, l = (i >> 3) & 63, ct = (i >> 9) & 7, ks = i >> 12;
            wf2outB[i] = f2b(w_f2out[(ks * 32 + 8 * (l >> 4) + e) * FD + ct * 16 + (l & 15)]);
        } else if (idx < 53248) {
            const int i = idx - 36864;
            const int e = i & 7, l = (i >> 3) & 63, ct = (i >> 9) & 7, ks = i >> 12;
            wdenseB[i] = f2b(w_dense[(ks * 32 + 8 * (l >> 4) + e) * FD + ct * 16 + (l & 15)]);
        }
    }
    // coalesced float4 reads, scattered ds_write_b16 ((k,col) -> frag slot)
#pragma unroll
    for (int v = 0; v < 8; ++v) {
        const int flat4 = (t + v * 512) * 4;             // 0..65532
        const float4 p = *(const float4*)&w_in2f[flat4];
        const float pv[4] = {p.x, p.y, p.z, p.w};
#pragma unroll
        for (int c = 0; c < 4; ++c) {
            const int flat = flat4 + c;
            const int k = flat >> 7, col = flat & 127;
            const int ks = k >> 5, kr = k & 31;
            const int slot = ((ks * 8 + (col >> 4)) * 64 + (kr >> 3) * 16 +
                              (col & 15)) * 8 + (kr & 7);
            s_w[slot] = f2b(pv[c]);
        }
    }
    __syncthreads();

    const int atom0 = blockIdx.x * 16;
    const int atom = atom0 + lr;
    const int z = zn[atom];
    const float* xrow = emb + (size_t)z * FD;
    bf16x8 a[4];
#pragma unroll
    for (int ks = 0; ks < 4; ++ks) {
        const int c0 = ks * 32 + lg * 8;
        const float4 p0 = *(const float4*)&xrow[c0];
        const float4 p1 = *(const float4*)&xrow[c0 + 4];
        if (w == 0) {
            *(float4*)&out[(size_t)atom * 256 + c0] = p0;
            *(float4*)&out[(size_t)atom * 256 + c0 + 4] = p1;
        }
        a[ks] = pack8(p0, p1);
    }
    f32x4 acc = {0.f, 0.f, 0.f, 0.f};
#pragma unroll
    for (int ks = 0; ks < 4; ++ks)
        acc = __builtin_amdgcn_mfma_f32_16x16x32_bf16(
            a[ks], *(const bf16x8*)&s_w[((ks * 8 + w) * 64 + lane) * 8],
            acc, 0, 0, 0);
    const int col = w * 16 + lr;
#pragma unroll
    for (int r = 0; r < 4; ++r)
        y[(size_t)(atom0 + lg * 4 + r) * FD + col] = acc[r];
}

// ---------------------------------------------------------------------------
// KB: continuous-filter conv (R23 base). R24: phases 3/4 specialized for the
// dominant Rt<=2 case via compile-time-unrolled bodies (rare et>=2 keeps the
// rolled fallback) — removes loop control + address recompute, enables
// cross-et ILP.
// ---------------------------------------------------------------------------
#define P3_BODY(ET)                                                           \
    {                                                                         \
        const int edge_ = (ET) * 16 + lr;                                     \
        const bf16x8 bfij_ = *(const bf16x8*)((char*)s_fij +                  \
               ((edge_ * 64 + lg * 16) ^ ((edge_ & 3) << 4)));                \
        const int exor_ = (edge_ & 7) << 4;                                   \
        _Pragma("unroll")                                                     \
        for (int i = 0; i < 2; ++i) {                                         \
            f32x4 acc_ = {0.f, 0.f, 0.f, 0.f};                                \
            acc_ = __builtin_amdgcn_mfma_f32_16x16x32_bf16(a1[i], bfij_,      \
                                                           acc_, 0, 0, 0);    \
            const int ft_ = 2 * w + i;                                        \
            const unsigned int lo_ = cvtpk(softplus_f(acc_[0]),               \
                                           softplus_f(acc_[1]));              \
            const unsigned int hi_ = cvtpk(softplus_f(acc_[2]),               \
                                           softplus_f(acc_[3]));              \
            const int byte0_ = edge_ * 256 + (ft_ * 16 + lg * 4) * 2;         \
            *(uint2*)((char*)s_h1 + (byte0_ ^ exor_)) = make_uint2(lo_, hi_); \
        }                                                                     \
    }

#define P4_BODY(J, ET)                                                        \
    {                                                                         \
        const int edge_ = (ET) * 16 + lr;                                     \
        const int ebase_ = edge_ * 256;                                       \
        const int exor_ = (edge_ & 7) << 4;                                   \
        bf16x8 bh_[4];                                                        \
        _Pragma("unroll")                                                     \
        for (int hs = 0; hs < 4; ++hs)                                        \
            bh_[hs] = *(const bf16x8*)((char*)s_h1 +                          \
                      ((ebase_ + hs * 64 + lg * 16) ^ exor_));                \
        f32x4 acc_ = {0.f, 0.f, 0.f, 0.f};                                    \
        _Pragma("unroll")                                                     \
        for (int hs = 0; hs < 4; ++hs)                                        \
            acc_ = __builtin_amdgcn_mfma_f32_16x16x32_bf16(a2f[hs], bh_[hs],  \
                                                           acc_, 0, 0, 0);    \
        const float Ce_ = s_C[edge_];                                         \
        const float4 yv_ = *(const float4*)&y[(size_t)((b << 9) +             \
                            s_nb[edge_]) * FD + c0];                          \
        part[J][0] += (acc_[0] + b2.x) * Ce_ * yv_.x;                         \
        part[J][1] += (acc_[1] + b2.y) * Ce_ * yv_.y;                         \
        part[J][2] += (acc_[2] + b2.z) * Ce_ * yv_.z;                         \
        part[J][3] += (acc_[3] + b2.w) * Ce_ * yv_.w;                         \
    }

__global__ __launch_bounds__(256, 4) void kB_conv(
    const float* __restrict__ pos, const float* __restrict__ cell,
    const float* __restrict__ coff, const float* __restrict__ nmask,
    const unsigned short* __restrict__ wf1tA,
    const unsigned short* __restrict__ wf2tA, const float* __restrict__ bf2,
    const int* __restrict__ nbr, const float* __restrict__ y,
    float* __restrict__ agg)
{
    const int t = threadIdx.x;
    const int w = t >> 6, lane = t & 63, lr = lane & 15, lg = lane >> 4;
    const int atom = (blockIdx.x & 7) * 512 + (blockIdx.x >> 3);
    const int b = atom >> 9;

    __shared__ unsigned short s_h1[NN * FD];   // 16KB, swizzled [edge][f] bf16
    __shared__ unsigned short s_fij[32 * 32];  // 2KB, swizzled [edge][g] bf16
    __shared__ float s_r[NN], s_C[NN];
    __shared__ int   s_nb[NN];
    __shared__ float s_bf2[FD];
    __shared__ int   s_cnt;

    if (t < FD) s_bf2[t] = bf2[t];

    bf16x8 a1[2];
#pragma unroll
    for (int i = 0; i < 2; ++i)
        a1[i] = *(const bf16x8*)&wf1tA[((2 * w + i) * 64 + lane) * 8];

    // ---- phase 1: distances + cutoff + compaction (wave 0 ONLY) ----
    if (w == 0) {
        const int k = lane;
        const int nb = nbr[atom * NN + k];
        const float m = nmask[atom * NN + k];
        const float* cb = cell + b * 9;
        const float* co = coff + (size_t)(atom * NN + k) * 3;
        const float ox = co[0]*cb[0] + co[1]*cb[3] + co[2]*cb[6];
        const float oy = co[0]*cb[1] + co[1]*cb[4] + co[2]*cb[7];
        const float oz = co[0]*cb[2] + co[1]*cb[5] + co[2]*cb[8];
        const float* pj = pos + (size_t)((b << 9) + nb) * 3;
        const float* pi = pos + (size_t)atom * 3;
        const float dx = pj[0] + ox - pi[0];
        const float dy = pj[1] + oy - pi[1];
        const float dz = pj[2] + oz - pi[2];
        const float d2 = dx*dx + dy*dy + dz*dz;
        const float r = sqrtf(m > 0.f ? d2 : 1.0f) * m;
        const float C = (r < 5.0f) ? m : 0.f;
        const bool act = (C != 0.f);
        const unsigned long long bal = __ballot(act);
        const int pre = __popcll(bal & ((1ull << k) - 1ull));
        const int cnt0 = __popcll(bal);
        if (act) { s_r[pre] = r; s_C[pre] = C; s_nb[pre] = nb; }
        if (k >= cnt0) { s_r[k] = 1e20f; s_C[k] = 0.f; s_nb[k] = 0; }
        if (k == 0) s_cnt = cnt0;
    }
    __syncthreads();   // s_r/C/nb, s_cnt, biases ready

    const int cnt = s_cnt;
    const int Rt = (cnt + 15) >> 4;

    const float DW = 5.0f / 24.0f;
    const float CO = -0.5f / (DW * DW);

    // ---- fij tile build (dedup): rows 0..31; K-slot 25 = 1.0 (bias) ----
    {
        const int row = t >> 3;            // 0..31
        const int g0  = (t & 7) * 4;       // 0,4,...,28
        const float re = s_r[row];
        float v[4];
#pragma unroll
        for (int c = 0; c < 4; ++c) {
            const int g = g0 + c;
            const float d = re - (float)g * DW;
            v[c] = (g < GAUSS) ? __expf(CO * d * d) : (g == GAUSS ? 1.0f : 0.f);
        }
        const unsigned int u0 = cvtpk(v[0], v[1]);
        const unsigned int u1 = cvtpk(v[2], v[3]);
        const int byte0 = (row * 64 + g0 * 2) ^ ((row & 3) << 4);
        *(uint2*)((char*)s_fij + byte0) = make_uint2(u0, u1);
    }
    __syncthreads();   // fij tile ready

    // ---- phase 3: h1^T tiles -> LDS (compile-time bodies for et 0/1) ----
    if (Rt > 0) P3_BODY(0);
    if (Rt > 1) P3_BODY(1);
    for (int et = 2; et < Rt; ++et) {      // rare: cnt > 32
        const int edge = et * 16 + lr;
        const float re = s_r[edge];
        bf16x8 bfij;
#pragma unroll
        for (int e = 0; e < 8; ++e) {
            const int g = 8 * lg + e;
            float v = 0.f;
            if (g < GAUSS) { const float d = re - (float)g * DW; v = __expf(CO * d * d); }
            else if (g == GAUSS) v = 1.0f;
            bfij[e] = (short)f2b(v);
        }
        const int exor = (edge & 7) << 4;
#pragma unroll
        for (int i = 0; i < 2; ++i) {
            f32x4 acc = {0.f, 0.f, 0.f, 0.f};
            acc = __builtin_amdgcn_mfma_f32_16x16x32_bf16(a1[i], bfij, acc, 0, 0, 0);
            const int ft = 2 * w + i;
            const unsigned int lo = cvtpk(softplus_f(acc[0]), softplus_f(acc[1]));
            const unsigned int hi = cvtpk(softplus_f(acc[2]), softplus_f(acc[3]));
            const int byte0 = edge * 256 + (ft * 16 + lg * 4) * 2;
            *(uint2*)((char*)s_h1 + (byte0 ^ exor)) = make_uint2(lo, hi);
        }
    }
    __syncthreads();   // h1 handoff

    // ---- phase 4: j OUTER; compile-time et bodies ----
    f32x4 part[2] = {{0,0,0,0},{0,0,0,0}};
#pragma unroll
    for (int j = 0; j < 2; ++j) {
        bf16x8 a2f[4];
#pragma unroll
        for (int hs = 0; hs < 4; ++hs)
            a2f[hs] = *(const bf16x8*)&wf2tA[((hs * 8 + 2 * w + j) * 64 + lane) * 8];
        const int c0 = (2 * w + j) * 16 + lg * 4;
        const float4 b2 = *(const float4*)&s_bf2[c0];
        if (Rt > 0) P4_BODY(j, 0);
        if (Rt > 1) P4_BODY(j, 1);
        for (int et = 2; et < Rt; ++et) P4_BODY(j, et);   // rare
    }
#pragma unroll
    for (int j = 0; j < 2; ++j) {
#pragma unroll
        for (int m = 1; m <= 8; m <<= 1) {
            part[j][0] += __shfl_xor(part[j][0], m);
            part[j][1] += __shfl_xor(part[j][1], m);
            part[j][2] += __shfl_xor(part[j][2], m);
            part[j][3] += __shfl_xor(part[j][3], m);
        }
    }
    if (lr == 0) {
#pragma unroll
        for (int j = 0; j < 2; ++j) {
            const float4 o = {part[j][0], part[j][1], part[j][2], part[j][3]};
            *(float4*)&agg[(size_t)atom * FD + (2 * w + j) * 16 + lg * 4] = o;
        }
    }
}

// ---------------------------------------------------------------------------
// KC = post-MLP + gather inversion (R22 config).
// ---------------------------------------------------------------------------
__global__ __launch_bounds__(512) void kC_post_gather(
    const float* __restrict__ agg, const int* __restrict__ label,
    const unsigned short* __restrict__ wf2outB, const float* __restrict__ b_f2out,
    const unsigned short* __restrict__ wdenseB, const float* __restrict__ b_dense,
    float* __restrict__ out)
{
    const int t = threadIdx.x;
    const int w = t >> 6, lane = t & 63, lr = lane & 15, lg = lane >> 4;
    const int n0 = blockIdx.x * 16;
    const int b = n0 >> 9;
    __shared__ unsigned short s_t[16 * FD];   // 4KB

    const int src = (b << 9) + label[n0 + lr];
    bf16x8 a[4];
#pragma unroll
    for (int ks = 0; ks < 4; ++ks) {
        const float* p = &agg[(size_t)src * FD + ks * 32 + lg * 8];
        a[ks] = pack8(*(const float4*)p, *(const float4*)(p + 4));
    }
    const int ct = w;
    {
        f32x4 acc = {0.f, 0.f, 0.f, 0.f};
#pragma unroll
        for (int ks = 0; ks < 4; ++ks)
            acc = __builtin_amdgcn_mfma_f32_16x16x32_bf16(
                a[ks], *(const bf16x8*)&wf2outB[((ks * 8 + ct) * 64 + lane) * 8],
                acc, 0, 0, 0);
        const int col = ct * 16 + lr;
        const float bias = b_f2out[col];
        const unsigned int lo = cvtpk(softplus_f(acc[0] + bias),
                                      softplus_f(acc[1] + bias));
        const unsigned int hi = cvtpk(softplus_f(acc[2] + bias),
                                      softplus_f(acc[3] + bias));
        const unsigned short v[4] = {
            (unsigned short)(lo & 0xFFFF), (unsigned short)(lo >> 16),
            (unsigned short)(hi & 0xFFFF), (unsigned short)(hi >> 16) };
#pragma unroll
        for (int r = 0; r < 4; ++r) {
            const int row = lg * 4 + r;
            *(unsigned short*)((char*)s_t + ((row * 256 + col * 2) ^ ((row & 7) << 4)))
                = v[r];
        }
    }
    __syncthreads();
    bf16x8 a2[4];
#pragma unroll
    for (int ks = 0; ks < 4; ++ks)
        a2[ks] = *(const bf16x8*)((char*)s_t +
                 ((lr * 256 + (ks * 32 + lg * 8) * 2) ^ ((lr & 7) << 4)));
    {
        f32x4 acc = {0.f, 0.f, 0.f, 0.f};
#pragma unroll
        for (int ks = 0; ks < 4; ++ks)
            acc = __builtin_amdgcn_mfma_f32_16x16x32_bf16(
                a2[ks], *(const bf16x8*)&wdenseB[((ks * 8 + ct) * 64 + lane) * 8],
                acc, 0, 0, 0);
        const int col = ct * 16 + lr;
        const float bias = b_dense[col];
#pragma unroll
        for (int r = 0; r < 4; ++r)
            out[(size_t)(n0 + lg * 4 + r) * 256 + FD + col] = acc[r] + bias;
    }
}

extern "C" void kernel_launch(void* const* d_in, const int* in_sizes, int n_in,
                              void* d_out, int out_size, void* d_ws, size_t ws_size,
                              hipStream_t stream)
{
    const float* positions = (const float*)d_in[0];
    const float* cell      = (const float*)d_in[1];
    const float* coff      = (const float*)d_in[2];
    const float* nmask     = (const float*)d_in[3];
    const float* emb       = (const float*)d_in[4];
    const float* wf1       = (const float*)d_in[5];
    const float* bf1       = (const float*)d_in[6];
    const float* wf2       = (const float*)d_in[7];
    const float* bf2       = (const float*)d_in[8];
    const float* w_in2f    = (const float*)d_in[9];
    const float* w_f2out   = (const float*)d_in[10];
    const float* b_f2out   = (const float*)d_in[11];
    const float* w_dense   = (const float*)d_in[12];
    const float* b_dense   = (const float*)d_in[13];
    const int*   zn        = (const int*)d_in[14];
    const int*   nbr       = (const int*)d_in[15];
    const int*   label     = (const int*)d_in[16];

    float* out = (float*)d_out;
    float* ws  = (float*)d_ws;
    float* y   = ws;                       // [4096,128]
    float* agg = ws + BN * FD;             // [4096,128]
    unsigned short* wf1tA   = (unsigned short*)(ws + 2 * BN * FD);  // 4096
    unsigned short* wf2tA   = wf1tA + 4096;                         // 16384
    unsigned short* wf2outB = wf2tA + 16384;                        // 16384
    unsigned short* wdenseB = wf2outB + 16384;                      // 16384

    hipLaunchKernelGGL(kA_prep_embed_y, dim3(BN / 16), dim3(512), 0, stream,
                       emb, zn, wf1, bf1, wf2, w_in2f, w_f2out, w_dense,
                       wf1tA, wf2tA, wf2outB, wdenseB, y, out);
    hipLaunchKernelGGL(kB_conv, dim3(BN), dim3(256), 0, stream,
                       positions, cell, coff, nmask, wf1tA, wf2tA, bf2,
                       nbr, y, agg);
    hipLaunchKernelGGL(kC_post_gather, dim3(BN / 16), dim3(512), 0, stream,
                       agg, label, wf2outB, b_f2out, wdenseB, b_dense, out);
}

// Round 25
// 35.320 us; speedup vs baseline: 1.0758x; 1.0758x over previous
//
#include <hip/hip_runtime.h>
#include <cmath>

#define BN 4096      // B*N
#define NN 64
#define GAUSS 25
#define FD 128

typedef __attribute__((ext_vector_type(8))) short bf16x8;
typedef __attribute__((ext_vector_type(4))) float f32x4;

__device__ __forceinline__ float softplus_f(float x) {
    const float t = __expf(-fabsf(x));
    return fmaxf(x, 0.f) + __logf(1.f + t);
}
// single-op packed bf16 convert (RNE)
__device__ __forceinline__ unsigned int cvtpk(float lo, float hi) {
    unsigned int r;
    asm("v_cvt_pk_bf16_f32 %0, %1, %2" : "=v"(r) : "v"(lo), "v"(hi));
    return r;
}
// scalar fallback (kA packing of scattered weight elems)
__device__ __forceinline__ unsigned short f2b(float f) {
    unsigned int u = __float_as_uint(f);
    unsigned int r = (u + 0x7FFFu + ((u >> 16) & 1u)) >> 16;
    return (unsigned short)r;
}
__device__ __forceinline__ bf16x8 pack8(const float4 p0, const float4 p1) {
    union { unsigned int u[4]; bf16x8 v; } r;
    r.u[0] = cvtpk(p0.x, p0.y); r.u[1] = cvtpk(p0.z, p0.w);
    r.u[2] = cvtpk(p1.x, p1.y); r.u[3] = cvtpk(p1.z, p1.w);
    return r.v;
}

// ---------------------------------------------------------------------------
// KA = k0 + k1 fused.  Grid 256 x 512.
// wf1tA row g==25 carries bf1 (bias folded into the h1 MFMA; fij
// supplies 1.0 at that K-slot).
// ---------------------------------------------------------------------------
__global__ __launch_bounds__(512) void kA_prep_embed_y(
    const float* __restrict__ emb, const int* __restrict__ zn,
    const float* __restrict__ wf1, const float* __restrict__ bf1,
    const float* __restrict__ wf2,
    const float* __restrict__ w_in2f, const float* __restrict__ w_f2out,
    const float* __restrict__ w_dense,
    unsigned short* __restrict__ wf1tA, unsigned short* __restrict__ wf2tA,
    unsigned short* __restrict__ wf2outB, unsigned short* __restrict__ wdenseB,
    float* __restrict__ y, float* __restrict__ out)
{
    const int t = threadIdx.x;
    const int w = t >> 6, lane = t & 63, lr = lane & 15, lg = lane >> 4;
    __shared__ unsigned short s_w[16384];   // 32KB: win2fB frags

    {
        const int idx = blockIdx.x * 512 + t;
        if (idx < 4096) {
            const int e = idx & 7, l = (idx >> 3) & 63, ft = idx >> 9;
            const int f = ft * 16 + (l & 15);
            const int g = 8 * (l >> 4) + e;
            wf1tA[idx] = (g < GAUSS) ? f2b(wf1[g * FD + f])
                       : (g == GAUSS ? f2b(bf1[f]) : (unsigned short)0);
        } else if (idx < 20480) {
            const int i = idx - 4096;
            const int e = i & 7, l = (i >> 3) & 63, ct = (i >> 9) & 7, ks = i >> 12;
            wf2tA[i] = f2b(wf2[(ks * 32 + 8 * (l >> 4) + e) * FD + ct * 16 + (l & 15)]);
        } else if (idx < 36864) {
            const int i = idx - 20480;
            const int e = i & 7, l = (i >> 3) & 63, ct = (i >> 9) & 7, ks = i >> 12;
            wf2outB[i] = f2b(w_f2out[(ks * 32 + 8 * (l >> 4) + e) * FD + ct * 16 + (l & 15)]);
        } else if (idx < 53248) {
            const int i = idx - 36864;
            const int e = i & 7, l = (i >> 3) & 63, ct = (i >> 9) & 7, ks = i >> 12;
            wdenseB[i] = f2b(w_dense[(ks * 32 + 8 * (l >> 4) + e) * FD + ct * 16 + (l & 15)]);
        }
    }
    for (int i = t * 32, end = t * 32 + 32; i < end; ++i) {
        const int e = i & 7, l = (i >> 3) & 63, ct = (i >> 9) & 7, ks = i >> 12;
        const int col = ct * 16 + (l & 15);
        const int k = ks * 32 + 8 * (l >> 4) + e;
        s_w[i] = f2b(w_in2f[k * FD + col]);
    }
    __syncthreads();

    const int atom0 = blockIdx.x * 16;
    const int atom = atom0 + lr;
    const int z = zn[atom];
    const float* xrow = emb + (size_t)z * FD;
    bf16x8 a[4];
#pragma unroll
    for (int ks = 0; ks < 4; ++ks) {
        const int c0 = ks * 32 + lg * 8;
        const float4 p0 = *(const float4*)&xrow[c0];
        const float4 p1 = *(const float4*)&xrow[c0 + 4];
        if (w == 0) {
            *(float4*)&out[(size_t)atom * 256 + c0] = p0;
            *(float4*)&out[(size_t)atom * 256 + c0 + 4] = p1;
        }
        a[ks] = pack8(p0, p1);
    }
    f32x4 acc = {0.f, 0.f, 0.f, 0.f};
#pragma unroll
    for (int ks = 0; ks < 4; ++ks)
        acc = __builtin_amdgcn_mfma_f32_16x16x32_bf16(
            a[ks], *(const bf16x8*)&s_w[((ks * 8 + w) * 64 + lane) * 8],
            acc, 0, 0, 0);
    const int col = w * 16 + lr;
#pragma unroll
    for (int r = 0; r < 4; ++r)
        y[(size_t)(atom0 + lg * 4 + r) * FD + col] = acc[r];
}

// ---------------------------------------------------------------------------
// KB: continuous-filter conv (R23 config — session best).
//  - 4 waves/atom (256 thr), wave w owns column-tiles {2w, 2w+1}.
//  - phase 1 on wave 0 only; cnt via LDS.
//  - fij gaussian tile deduplicated (built once, XOR-swizzled; K-slot 25=1.0
//    folds bf1 via wf1tA row 25).
//  - all bf16 packing via v_cvt_pk_bf16_f32.
// ---------------------------------------------------------------------------
__global__ __launch_bounds__(256, 4) void kB_conv(
    const float* __restrict__ pos, const float* __restrict__ cell,
    const float* __restrict__ coff, const float* __restrict__ nmask,
    const unsigned short* __restrict__ wf1tA,
    const unsigned short* __restrict__ wf2tA, const float* __restrict__ bf2,
    const int* __restrict__ nbr, const float* __restrict__ y,
    float* __restrict__ agg)
{
    const int t = threadIdx.x;
    const int w = t >> 6, lane = t & 63, lr = lane & 15, lg = lane >> 4;
    const int atom = (blockIdx.x & 7) * 512 + (blockIdx.x >> 3);
    const int b = atom >> 9;

    __shared__ unsigned short s_h1[NN * FD];   // 16KB, swizzled [edge][f] bf16
    __shared__ unsigned short s_fij[32 * 32];  // 2KB, swizzled [edge][g] bf16
    __shared__ float s_r[NN], s_C[NN];
    __shared__ int   s_nb[NN];
    __shared__ float s_bf2[FD];
    __shared__ int   s_cnt;

    if (t < FD) s_bf2[t] = bf2[t];

    bf16x8 a1[2];
#pragma unroll
    for (int i = 0; i < 2; ++i)
        a1[i] = *(const bf16x8*)&wf1tA[((2 * w + i) * 64 + lane) * 8];

    // ---- phase 1: distances + cutoff + compaction (wave 0 ONLY) ----
    if (w == 0) {
        const int k = lane;
        const int nb = nbr[atom * NN + k];
        const float m = nmask[atom * NN + k];
        const float* cb = cell + b * 9;
        const float* co = coff + (size_t)(atom * NN + k) * 3;
        const float ox = co[0]*cb[0] + co[1]*cb[3] + co[2]*cb[6];
        const float oy = co[0]*cb[1] + co[1]*cb[4] + co[2]*cb[7];
        const float oz = co[0]*cb[2] + co[1]*cb[5] + co[2]*cb[8];
        const float* pj = pos + (size_t)((b << 9) + nb) * 3;
        const float* pi = pos + (size_t)atom * 3;
        const float dx = pj[0] + ox - pi[0];
        const float dy = pj[1] + oy - pi[1];
        const float dz = pj[2] + oz - pi[2];
        const float d2 = dx*dx + dy*dy + dz*dz;
        const float r = sqrtf(m > 0.f ? d2 : 1.0f) * m;
        const float C = (r < 5.0f) ? m : 0.f;
        const bool act = (C != 0.f);
        const unsigned long long bal = __ballot(act);
        const int pre = __popcll(bal & ((1ull << k) - 1ull));
        const int cnt0 = __popcll(bal);
        if (act) { s_r[pre] = r; s_C[pre] = C; s_nb[pre] = nb; }
        if (k >= cnt0) { s_r[k] = 1e20f; s_C[k] = 0.f; s_nb[k] = 0; }
        if (k == 0) s_cnt = cnt0;
    }
    __syncthreads();   // s_r/C/nb, s_cnt, biases ready

    const int cnt = s_cnt;
    const int Rt = (cnt + 15) >> 4;

    const float DW = 5.0f / 24.0f;
    const float CO = -0.5f / (DW * DW);

    // ---- fij tile build (dedup): 256 threads x 4 slots, rows 0..31;
    //      K-slot 25 = 1.0 (bias row) ----
    {
        const int row = t >> 3;            // 0..31
        const int g0  = (t & 7) * 4;       // 0,4,...,28
        const float re = s_r[row];
        float v[4];
#pragma unroll
        for (int c = 0; c < 4; ++c) {
            const int g = g0 + c;
            const float d = re - (float)g * DW;
            v[c] = (g < GAUSS) ? __expf(CO * d * d) : (g == GAUSS ? 1.0f : 0.f);
        }
        const unsigned int u0 = cvtpk(v[0], v[1]);
        const unsigned int u1 = cvtpk(v[2], v[3]);
        const int byte0 = (row * 64 + g0 * 2) ^ ((row & 3) << 4);
        *(uint2*)((char*)s_fij + byte0) = make_uint2(u0, u1);
    }
    __syncthreads();   // fij tile ready

    // ---- phase 3: h1^T tiles -> LDS (each wave its 2 f-tiles) ----
    for (int et = 0; et < Rt; ++et) {
        const int edge = et * 16 + lr;
        bf16x8 bfij;
        if (et < 2) {
            bfij = *(const bf16x8*)((char*)s_fij +
                   ((edge * 64 + lg * 16) ^ ((edge & 3) << 4)));
        } else {                           // rare: cnt > 32
            const float re = s_r[edge];
#pragma unroll
            for (int e = 0; e < 8; ++e) {
                const int g = 8 * lg + e;
                float v = 0.f;
                if (g < GAUSS) { const float d = re - (float)g * DW; v = __expf(CO * d * d); }
                else if (g == GAUSS) v = 1.0f;
                bfij[e] = (short)f2b(v);
            }
        }
        const int exor = (edge & 7) << 4;
#pragma unroll
        for (int i = 0; i < 2; ++i) {
            f32x4 acc = {0.f, 0.f, 0.f, 0.f};
            acc = __builtin_amdgcn_mfma_f32_16x16x32_bf16(a1[i], bfij, acc, 0, 0, 0);
            const int ft = 2 * w + i;
            const unsigned int lo = cvtpk(softplus_f(acc[0]), softplus_f(acc[1]));
            const unsigned int hi = cvtpk(softplus_f(acc[2]), softplus_f(acc[3]));
            const int byte0 = edge * 256 + (ft * 16 + lg * 4) * 2;
            *(uint2*)((char*)s_h1 + (byte0 ^ exor)) = make_uint2(lo, hi);
        }
    }
    __syncthreads();   // h1 handoff

    // ---- phase 4: j OUTER (a2f et-invariant), et inner ----
    f32x4 part[2] = {{0,0,0,0},{0,0,0,0}};
#pragma unroll
    for (int j = 0; j < 2; ++j) {
        bf16x8 a2f[4];
#pragma unroll
        for (int hs = 0; hs < 4; ++hs)
            a2f[hs] = *(const bf16x8*)&wf2tA[((hs * 8 + 2 * w + j) * 64 + lane) * 8];
        const int c0 = (2 * w + j) * 16 + lg * 4;
        const float4 b2 = *(const float4*)&s_bf2[c0];
        for (int et = 0; et < Rt; ++et) {
            const int edge = et * 16 + lr;
            const int ebase = edge * 256;
            const int exor = (edge & 7) << 4;
            bf16x8 bh[4];
#pragma unroll
            for (int hs = 0; hs < 4; ++hs)
                bh[hs] = *(const bf16x8*)((char*)s_h1 + ((ebase + hs * 64 + lg * 16) ^ exor));
            f32x4 acc = {0.f, 0.f, 0.f, 0.f};
#pragma unroll
            for (int hs = 0; hs < 4; ++hs)
                acc = __builtin_amdgcn_mfma_f32_16x16x32_bf16(a2f[hs], bh[hs], acc, 0, 0, 0);
            const float Ce = s_C[edge];
            const float4 yv = *(const float4*)&y[(size_t)((b << 9) + s_nb[edge]) * FD + c0];
            part[j][0] += (acc[0] + b2.x) * Ce * yv.x;
            part[j][1] += (acc[1] + b2.y) * Ce * yv.y;
            part[j][2] += (acc[2] + b2.z) * Ce * yv.z;
            part[j][3] += (acc[3] + b2.w) * Ce * yv.w;
        }
    }
#pragma unroll
    for (int j = 0; j < 2; ++j) {
#pragma unroll
        for (int m = 1; m <= 8; m <<= 1) {
            part[j][0] += __shfl_xor(part[j][0], m);
            part[j][1] += __shfl_xor(part[j][1], m);
            part[j][2] += __shfl_xor(part[j][2], m);
            part[j][3] += __shfl_xor(part[j][3], m);
        }
    }
    if (lr == 0) {
#pragma unroll
        for (int j = 0; j < 2; ++j) {
            const float4 o = {part[j][0], part[j][1], part[j][2], part[j][3]};
            *(float4*)&agg[(size_t)atom * FD + (2 * w + j) * 16 + lg * 4] = o;
        }
    }
}

// ---------------------------------------------------------------------------
// KC = post-MLP + gather inversion (R22 config).
// ---------------------------------------------------------------------------
__global__ __launch_bounds__(512) void kC_post_gather(
    const float* __restrict__ agg, const int* __restrict__ label,
    const unsigned short* __restrict__ wf2outB, const float* __restrict__ b_f2out,
    const unsigned short* __restrict__ wdenseB, const float* __restrict__ b_dense,
    float* __restrict__ out)
{
    const int t = threadIdx.x;
    const int w = t >> 6, lane = t & 63, lr = lane & 15, lg = lane >> 4;
    const int n0 = blockIdx.x * 16;
    const int b = n0 >> 9;
    __shared__ unsigned short s_t[16 * FD];   // 4KB

    const int src = (b << 9) + label[n0 + lr];
    bf16x8 a[4];
#pragma unroll
    for (int ks = 0; ks < 4; ++ks) {
        const float* p = &agg[(size_t)src * FD + ks * 32 + lg * 8];
        a[ks] = pack8(*(const float4*)p, *(const float4*)(p + 4));
    }
    const int ct = w;
    {
        f32x4 acc = {0.f, 0.f, 0.f, 0.f};
#pragma unroll
        for (int ks = 0; ks < 4; ++ks)
            acc = __builtin_amdgcn_mfma_f32_16x16x32_bf16(
                a[ks], *(const bf16x8*)&wf2outB[((ks * 8 + ct) * 64 + lane) * 8],
                acc, 0, 0, 0);
        const int col = ct * 16 + lr;
        const float bias = b_f2out[col];
        const unsigned int lo = cvtpk(softplus_f(acc[0] + bias),
                                      softplus_f(acc[1] + bias));
        const unsigned int hi = cvtpk(softplus_f(acc[2] + bias),
                                      softplus_f(acc[3] + bias));
        const unsigned short v[4] = {
            (unsigned short)(lo & 0xFFFF), (unsigned short)(lo >> 16),
            (unsigned short)(hi & 0xFFFF), (unsigned short)(hi >> 16) };
#pragma unroll
        for (int r = 0; r < 4; ++r) {
            const int row = lg * 4 + r;
            *(unsigned short*)((char*)s_t + ((row * 256 + col * 2) ^ ((row & 7) << 4)))
                = v[r];
        }
    }
    __syncthreads();
    bf16x8 a2[4];
#pragma unroll
    for (int ks = 0; ks < 4; ++ks)
        a2[ks] = *(const bf16x8*)((char*)s_t +
                 ((lr * 256 + (ks * 32 + lg * 8) * 2) ^ ((lr & 7) << 4)));
    {
        f32x4 acc = {0.f, 0.f, 0.f, 0.f};
#pragma unroll
        for (int ks = 0; ks < 4; ++ks)
            acc = __builtin_amdgcn_mfma_f32_16x16x32_bf16(
                a2[ks], *(const bf16x8*)&wdenseB[((ks * 8 + ct) * 64 + lane) * 8],
                acc, 0, 0, 0);
        const int col = ct * 16 + lr;
        const float bias = b_dense[col];
#pragma unroll
        for (int r = 0; r < 4; ++r)
            out[(size_t)(n0 + lg * 4 + r) * 256 + FD + col] = acc[r] + bias;
    }
}

extern "C" void kernel_launch(void* const* d_in, const int* in_sizes, int n_in,
                              void* d_out, int out_size, void* d_ws, size_t ws_size,
                              hipStream_t stream)
{
    const float* positions = (const float*)d_in[0];
    const float* cell      = (const float*)d_in[1];
    const float* coff      = (const float*)d_in[2];
    const float* nmask     = (const float*)d_in[3];
    const float* emb       = (const float*)d_in[4];
    const float* wf1       = (const float*)d_in[5];
    const float* bf1       = (const float*)d_in[6];
    const float* wf2       = (const float*)d_in[7];
    const float* bf2       = (const float*)d_in[8];
    const float* w_in2f    = (const float*)d_in[9];
    const float* w_f2out   = (const float*)d_in[10];
    const float* b_f2out   = (const float*)d_in[11];
    const float* w_dense   = (const float*)d_in[12];
    const float* b_dense   = (const float*)d_in[13];
    const int*   zn        = (const int*)d_in[14];
    const int*   nbr       = (const int*)d_in[15];
    const int*   label     = (const int*)d_in[16];

    float* out = (float*)d_out;
    float* ws  = (float*)d_ws;
    float* y   = ws;                       // [4096,128]
    float* agg = ws + BN * FD;             // [4096,128]
    unsigned short* wf1tA   = (unsigned short*)(ws + 2 * BN * FD);  // 4096
    unsigned short* wf2tA   = wf1tA + 4096;                         // 16384
    unsigned short* wf2outB = wf2tA + 16384;                        // 16384
    unsigned short* wdenseB = wf2outB + 16384;                      // 16384

    hipLaunchKernelGGL(kA_prep_embed_y, dim3(BN / 16), dim3(512), 0, stream,
                       emb, zn, wf1, bf1, wf2, w_in2f, w_f2out, w_dense,
                       wf1tA, wf2tA, wf2outB, wdenseB, y, out);
    hipLaunchKernelGGL(kB_conv, dim3(BN), dim3(256), 0, stream,
                       positions, cell, coff, nmask, wf1tA, wf2tA, bf2,
                       nbr, y, agg);
    hipLaunchKernelGGL(kC_post_gather, dim3(BN / 16), dim3(512), 0, stream,
                       agg, label, wf2outB, b_f2out, wdenseB, b_dense, out);
}